// Round 3
// baseline (462.637 us; speedup 1.0000x reference)
//
#include <hip/hip_runtime.h>
#include <math.h>

// SparseFocalModulation — sparsity-aware, 9-dispatch pipeline.
// Facts exploited: idx[center][i] == i (dense identity), non-center offsets
// ~0.36% occupied (~107 valid pairs per offset at N=30000).

#define PL 1024   // plist capacity (pairs) per sparse block; expected ~18

__device__ __forceinline__ float gelu_exact(float x) {
    return 0.5f * x * (1.0f + erff(x * 0.70710678118654752440f));
}

// ---------------- K1: xf = feat @ f_W + f_b ; split into q / ctx / gates ----
__global__ __launch_bounds__(256) void k_fused_in(
    const float* __restrict__ feat, const float* __restrict__ fW,
    const float* __restrict__ fb, float* __restrict__ q,
    float* __restrict__ ctx, float* __restrict__ gates, int N)
{
    __shared__ float sW[64 * 132];
    __shared__ float sb[132];
    for (int t = threadIdx.x; t < 64 * 132; t += 256) sW[t] = fW[t];
    if (threadIdx.x < 132) sb[threadIdx.x] = fb[threadIdx.x];
    __syncthreads();
    const int lane = threadIdx.x & 63;
    const int wid = blockIdx.x * 4 + (threadIdx.x >> 6);
    const int nw  = gridDim.x * 4;
    const int gcol = 128 + (lane & 3);
    for (int r = wid; r < N; r += nw) {
        float fv = feat[r * 64 + lane];
        float aq = sb[lane];
        float ac = sb[64 + lane];
        float ag = sb[gcol];
        #pragma unroll
        for (int k = 0; k < 64; ++k) {
            float f = __shfl(fv, k);
            aq = fmaf(f, sW[k * 132 + lane], aq);
            ac = fmaf(f, sW[k * 132 + 64 + lane], ac);
            ag = fmaf(f, sW[k * 132 + gcol], ag);
        }
        q[r * 64 + lane]   = aq;
        ctx[r * 64 + lane] = ac;
        if (lane < 4) gates[r * 4 + lane] = ag;
    }
}

// ---------------- K2: sparse non-center offsets -> atomicAdd into sbuf ------
__global__ __launch_bounds__(256) void k_sparse(
    const float* __restrict__ ctx, const int* __restrict__ idx,
    const float* __restrict__ W, float* __restrict__ sbuf,
    int N, int center, int nchunk, int seg)
{
    const int o = blockIdx.x / nchunk;
    if (o == center) return;
    const int chunk = blockIdx.x % nchunk;

    __shared__ int   plist[2 * PL];
    __shared__ int   pcnt;
    __shared__ float sW[4096];
    if (threadIdx.x == 0) pcnt = 0;
    __syncthreads();

    const int start = chunk * seg;
    const int end   = min(N, start + seg);
    const int* row  = idx + (size_t)o * N;
    if (((N | start) & 3) == 0) {
        const int4* row4 = reinterpret_cast<const int4*>(row + start);
        const int n4 = (end - start) >> 2;
        for (int t = threadIdx.x; t < n4; t += 256) {
            int4 v = row4[t];
            int base = start + t * 4;
            if (v.x >= 0) { int p = atomicAdd(&pcnt, 1); if (p < PL) { plist[2*p] = base;     plist[2*p+1] = v.x; } }
            if (v.y >= 0) { int p = atomicAdd(&pcnt, 1); if (p < PL) { plist[2*p] = base + 1; plist[2*p+1] = v.y; } }
            if (v.z >= 0) { int p = atomicAdd(&pcnt, 1); if (p < PL) { plist[2*p] = base + 2; plist[2*p+1] = v.z; } }
            if (v.w >= 0) { int p = atomicAdd(&pcnt, 1); if (p < PL) { plist[2*p] = base + 3; plist[2*p+1] = v.w; } }
        }
    } else {
        for (int t = start + threadIdx.x; t < end; t += 256) {
            int j = row[t];
            if (j >= 0) { int p = atomicAdd(&pcnt, 1); if (p < PL) { plist[2*p] = t; plist[2*p+1] = j; } }
        }
    }
    __syncthreads();

    const int cnt = min(pcnt, PL);
    if (cnt == 0) return;                      // most blocks: skip W load
    for (int t = threadIdx.x; t < 4096; t += 256) sW[t] = W[(size_t)o * 4096 + t];
    __syncthreads();

    const int lane = threadIdx.x & 63;
    const int lwid = threadIdx.x >> 6;
    for (int p = lwid; p < cnt; p += 4) {
        int i = plist[2 * p];
        int j = plist[2 * p + 1];
        float cv  = ctx[j * 64 + lane];
        float acc = 0.0f;
        #pragma unroll
        for (int c = 0; c < 64; ++c)
            acc = fmaf(__shfl(cv, c), sW[c * 64 + lane], acc);
        atomicAdd(&sbuf[(size_t)i * 64 + lane], acc);
    }
}

// ------- K3: y = center-matvec + sbuf + b; ln = LN(gelu(y)); opt. pooling ---
__global__ __launch_bounds__(256) void k_post(
    const float* __restrict__ cin, float* __restrict__ sbuf,
    const float* __restrict__ W, const float* __restrict__ b,
    const float* __restrict__ g, const float* __restrict__ be,
    const int* __restrict__ bid, float* __restrict__ lnout,
    float* __restrict__ psum, float* __restrict__ pcnts,
    int N, int center, int zero_sbuf, int do_pool)
{
    __shared__ float sW[4096];
    __shared__ float sb[64], sg[64], sbe[64];
    __shared__ float red[4 * 4 * 64];
    __shared__ float redc[4 * 4];
    const float* Wc = W + (size_t)center * 4096;
    for (int t = threadIdx.x; t < 4096; t += 256) sW[t] = Wc[t];
    if (threadIdx.x < 64) {
        sb[threadIdx.x]  = b[threadIdx.x];
        sg[threadIdx.x]  = g[threadIdx.x];
        sbe[threadIdx.x] = be[threadIdx.x];
    }
    __syncthreads();

    const int lane = threadIdx.x & 63;
    const int lwid = threadIdx.x >> 6;
    const int wid  = blockIdx.x * 4 + lwid;
    const int nw   = gridDim.x * 4;
    float a0 = 0, a1 = 0, a2 = 0, a3 = 0;
    float c0 = 0, c1 = 0, c2 = 0, c3 = 0;

    for (int r = wid; r < N; r += nw) {
        float cv  = cin[r * 64 + lane];
        float acc = sb[lane] + sbuf[(size_t)r * 64 + lane];
        if (zero_sbuf) sbuf[(size_t)r * 64 + lane] = 0.0f;
        #pragma unroll
        for (int c = 0; c < 64; ++c)
            acc = fmaf(__shfl(cv, c), sW[c * 64 + lane], acc);
        float v = gelu_exact(acc);
        float s = v;
        #pragma unroll
        for (int m = 1; m < 64; m <<= 1) s += __shfl_xor(s, m);
        const float mean = s * 0.015625f;
        const float d = v - mean;
        float vs = d * d;
        #pragma unroll
        for (int m = 1; m < 64; m <<= 1) vs += __shfl_xor(vs, m);
        const float ln = d * rsqrtf(vs * 0.015625f + 1e-5f) * sg[lane] + sbe[lane];
        lnout[r * 64 + lane] = ln;
        if (do_pool) {
            int bb = bid[r];
            if      (bb == 0) { a0 += ln; c0 += 1.0f; }
            else if (bb == 1) { a1 += ln; c1 += 1.0f; }
            else if (bb == 2) { a2 += ln; c2 += 1.0f; }
            else              { a3 += ln; c3 += 1.0f; }
        }
    }

    if (do_pool) {
        red[(lwid * 4 + 0) * 64 + lane] = a0;
        red[(lwid * 4 + 1) * 64 + lane] = a1;
        red[(lwid * 4 + 2) * 64 + lane] = a2;
        red[(lwid * 4 + 3) * 64 + lane] = a3;
        if (lane == 0) {
            redc[lwid * 4 + 0] = c0; redc[lwid * 4 + 1] = c1;
            redc[lwid * 4 + 2] = c2; redc[lwid * 4 + 3] = c3;
        }
        __syncthreads();
        if (lwid == 0) {
            #pragma unroll
            for (int bb = 0; bb < 4; ++bb) {
                float sum = red[(0 * 4 + bb) * 64 + lane] + red[(1 * 4 + bb) * 64 + lane]
                          + red[(2 * 4 + bb) * 64 + lane] + red[(3 * 4 + bb) * 64 + lane];
                atomicAdd(&psum[bb * 64 + lane], sum);
            }
        }
        if (threadIdx.x == 0) {
            #pragma unroll
            for (int bb = 0; bb < 4; ++bb) {
                float cc = redc[0 * 4 + bb] + redc[1 * 4 + bb] + redc[2 * 4 + bb] + redc[3 * 4 + bb];
                atomicAdd(&pcnts[bb], cc);
            }
        }
    }
}

// ---------------- K4: epilogue --------------------------------------------
__global__ __launch_bounds__(256) void k_final(
    const float* __restrict__ ln0, const float* __restrict__ ln1,
    const float* __restrict__ ln2, const float* __restrict__ gates,
    const float* __restrict__ q, const int* __restrict__ bid,
    const float* __restrict__ psum, const float* __restrict__ pcnts,
    const float* __restrict__ hW, const float* __restrict__ hb,
    const float* __restrict__ pW, const float* __restrict__ pb,
    float* __restrict__ out, int N)
{
    __shared__ float sH[4096], sP[4096];
    __shared__ float spool[256];
    __shared__ float shb[64], spb[64];
    for (int t = threadIdx.x; t < 4096; t += 256) { sH[t] = hW[t]; sP[t] = pW[t]; }
    if (threadIdx.x < 64) { shb[threadIdx.x] = hb[threadIdx.x]; spb[threadIdx.x] = pb[threadIdx.x]; }
    if (threadIdx.x < 256) {
        int bb = threadIdx.x >> 6;
        spool[threadIdx.x] = gelu_exact(psum[threadIdx.x] / pcnts[bb]);
    }
    __syncthreads();

    const int lane = threadIdx.x & 63;
    const int wid = blockIdx.x * 4 + (threadIdx.x >> 6);
    const int nw  = gridDim.x * 4;
    for (int r = wid; r < N; r += nw) {
        const float4 gt = reinterpret_cast<const float4*>(gates)[r];
        const int bb = bid[r];
        float v = ln0[r * 64 + lane] * gt.x + ln1[r * 64 + lane] * gt.y
                + ln2[r * 64 + lane] * gt.z + spool[bb * 64 + lane] * gt.w;
        float t1 = shb[lane];
        #pragma unroll
        for (int c = 0; c < 64; ++c)
            t1 = fmaf(__shfl(v, c), sH[c * 64 + lane], t1);
        float u = q[r * 64 + lane] * t1;   // q aliases `out`; own-row read precedes write
        float o = spb[lane];
        #pragma unroll
        for (int c = 0; c < 64; ++c)
            o = fmaf(__shfl(u, c), sP[c * 64 + lane], o);
        out[r * 64 + lane] = o;
    }
}

// ---------------------------------------------------------------------------
extern "C" void kernel_launch(void* const* d_in, const int* in_sizes, int n_in,
                              void* d_out, int out_size, void* d_ws, size_t ws_size,
                              hipStream_t stream)
{
    const float* feat = (const float*)d_in[0];
    const float* fW   = (const float*)d_in[1];
    const float* fb   = (const float*)d_in[2];
    const float* hW   = (const float*)d_in[3];
    const float* hb   = (const float*)d_in[4];
    const float* pW   = (const float*)d_in[5];
    const float* pb   = (const float*)d_in[6];
    const int*   bid  = (const int*)d_in[7];
    const float* w[3]  = {(const float*)d_in[8],  (const float*)d_in[13], (const float*)d_in[18]};
    const float* bc[3] = {(const float*)d_in[9],  (const float*)d_in[14], (const float*)d_in[19]};
    const float* g[3]  = {(const float*)d_in[10], (const float*)d_in[15], (const float*)d_in[20]};
    const float* be[3] = {(const float*)d_in[11], (const float*)d_in[16], (const float*)d_in[21]};
    const int*  idx[3] = {(const int*)d_in[12],   (const int*)d_in[17],   (const int*)d_in[22]};

    const int N = in_sizes[0] / 64;

    // Workspace layout (floats). q lives in d_out; ln2 reuses ctx0's buffer.
    float* ws     = (float*)d_ws;
    float* sbuf   = ws;                          // N*64, zeroed once
    float* psum   = sbuf + (size_t)N * 64;       // 256, zeroed
    float* pcnts  = psum + 256;                  // 4, zeroed
    float* gates  = pcnts + 4;                   // N*4
    float* ctx0   = gates + (size_t)N * 4;       // N*64 (becomes ln2)
    float* ln0    = ctx0 + (size_t)N * 64;       // N*64
    float* ln1    = ln0 + (size_t)N * 64;        // N*64
    float* ln2    = ctx0;                        // alias: ctx0 dead after level 0
    float* q      = (float*)d_out;               // alias: epilogue reads then writes

    hipMemsetAsync(sbuf, 0, ((size_t)N * 64 + 260) * sizeof(float), stream);

    const dim3 blk(256);
    const int GR = 512;

    k_fused_in<<<GR, blk, 0, stream>>>(feat, fW, fb, q, ctx0, gates, N);

    const int Ks[3] = {27, 125, 343};
    const int Cs[3] = {16, 8, 6};
    const float* cins[3] = {ctx0, ln0, ln1};
    float*       lns[3]  = {ln0, ln1, ln2};
    for (int l = 0; l < 3; ++l) {
        const int K = Ks[l], C = Cs[l];
        const int center = (K - 1) / 2;
        const int seg = (((N + C - 1) / C) + 3) & ~3;
        k_sparse<<<K * C, blk, 0, stream>>>(cins[l], idx[l], w[l], sbuf, N, center, C, seg);
        k_post  <<<GR,    blk, 0, stream>>>(cins[l], sbuf, w[l], bc[l], g[l], be[l], bid,
                                            lns[l], psum, pcnts, N, center,
                                            (l < 2) ? 1 : 0, (l == 2) ? 1 : 0);
    }

    k_final<<<GR, blk, 0, stream>>>(ln0, ln1, ln2, gates, q, bid, psum, pcnts,
                                    hW, hb, pW, pb, (float*)d_out, N);
}

// Round 4
// 388.941 us; speedup vs baseline: 1.1895x; 1.1895x over previous
//
#include <hip/hip_runtime.h>
#include <math.h>

// SparseFocalModulation — round 4: dense kernels rebuilt around
// weights-in-VGPR + LDS-broadcast matvec (no ds_bpermute in hot loops).

#define PL 1024   // plist capacity (pairs) per sparse block; expected ~18

__device__ __forceinline__ float gelu_exact(float x) {
    return 0.5f * x * (1.0f + erff(x * 0.70710678118654752440f));
}

// acc[m] += sum_k sin[m*64+k] * w[k]   (sin: wave-private LDS, broadcast reads)
template<int NACC>
__device__ __forceinline__ void matvec_bcast(const float* sin, const float (&w)[64], float (&acc)[NACC]) {
    #pragma unroll
    for (int kg = 0; kg < 16; ++kg) {
        #pragma unroll
        for (int m = 0; m < NACC; ++m) {
            const float4 iv = *(const float4*)(sin + m * 64 + kg * 4);
            acc[m] = fmaf(iv.x, w[kg * 4 + 0], acc[m]);
            acc[m] = fmaf(iv.y, w[kg * 4 + 1], acc[m]);
            acc[m] = fmaf(iv.z, w[kg * 4 + 2], acc[m]);
            acc[m] = fmaf(iv.w, w[kg * 4 + 3], acc[m]);
        }
    }
}

// ---------------- K1: xf = feat @ f_W + f_b ; split into q / ctx / gates ----
__global__ __launch_bounds__(256) void k_fused_in(
    const float* __restrict__ feat, const float* __restrict__ fW,
    const float* __restrict__ fb, float* __restrict__ q,
    float* __restrict__ ctx, float* __restrict__ gates, int N)
{
    __shared__ float sIn[4][256];
    const int lane = threadIdx.x & 63;
    const int wv   = threadIdx.x >> 6;
    float* sin = sIn[wv];

    float wq[64], wc[64];
    #pragma unroll
    for (int k = 0; k < 64; ++k) {
        wq[k] = fW[k * 132 + lane];
        wc[k] = fW[k * 132 + 64 + lane];
    }
    const int g    = lane & 3;
    const int kblk = lane >> 2;           // 16 k-blocks of 4
    float wg[4];
    #pragma unroll
    for (int kk = 0; kk < 4; ++kk)
        wg[kk] = fW[(kblk * 4 + kk) * 132 + 128 + g];
    const float bq = fb[lane], bc = fb[64 + lane], bg = fb[128 + g];

    const int wid  = blockIdx.x * 4 + wv;
    const int nw   = gridDim.x * 4;
    const int ngrp = (N + 3) >> 2;
    for (int grp = wid; grp < ngrp; grp += nw) {
        const int r0 = grp * 4;
        const int nr = min(4, N - r0);
        #pragma unroll
        for (int m = 0; m < 4; ++m) {
            int r = r0 + ((m < nr) ? m : 0);
            sin[m * 64 + lane] = feat[(size_t)r * 64 + lane];
        }
        float aq[4] = {bq, bq, bq, bq};
        float ac[4] = {bc, bc, bc, bc};
        matvec_bcast<4>(sin, wq, aq);
        matvec_bcast<4>(sin, wc, ac);
        float ag[4];
        #pragma unroll
        for (int m = 0; m < 4; ++m) {
            const float4 gi = *(const float4*)(sin + m * 64 + kblk * 4);
            float s = gi.x * wg[0] + gi.y * wg[1] + gi.z * wg[2] + gi.w * wg[3];
            s += __shfl_xor(s, 4);
            s += __shfl_xor(s, 8);
            s += __shfl_xor(s, 16);
            s += __shfl_xor(s, 32);
            ag[m] = s + bg;
        }
        #pragma unroll
        for (int m = 0; m < 4; ++m) {
            if (m < nr) {
                q[(size_t)(r0 + m) * 64 + lane]   = aq[m];
                ctx[(size_t)(r0 + m) * 64 + lane] = ac[m];
                if (lane < 4) gates[(size_t)(r0 + m) * 4 + lane] = ag[m];
            }
        }
    }
}

// ---------------- K2: sparse non-center offsets -> atomicAdd into sbuf ------
__global__ __launch_bounds__(256) void k_sparse(
    const float* __restrict__ ctx, const int* __restrict__ idx,
    const float* __restrict__ W, float* __restrict__ sbuf,
    int N, int center, int nchunk, int seg)
{
    const int o = blockIdx.x / nchunk;
    if (o == center) return;
    const int chunk = blockIdx.x % nchunk;

    __shared__ int   plist[2 * PL];
    __shared__ int   pcnt;
    __shared__ float sW[4096];
    if (threadIdx.x == 0) pcnt = 0;
    __syncthreads();

    const int start = chunk * seg;
    const int end   = min(N, start + seg);
    const int* row  = idx + (size_t)o * N;
    if (((N | start) & 3) == 0) {
        const int4* row4 = reinterpret_cast<const int4*>(row + start);
        const int n4 = (end - start) >> 2;
        for (int t = threadIdx.x; t < n4; t += 256) {
            int4 v = row4[t];
            int base = start + t * 4;
            if (v.x >= 0) { int p = atomicAdd(&pcnt, 1); if (p < PL) { plist[2*p] = base;     plist[2*p+1] = v.x; } }
            if (v.y >= 0) { int p = atomicAdd(&pcnt, 1); if (p < PL) { plist[2*p] = base + 1; plist[2*p+1] = v.y; } }
            if (v.z >= 0) { int p = atomicAdd(&pcnt, 1); if (p < PL) { plist[2*p] = base + 2; plist[2*p+1] = v.z; } }
            if (v.w >= 0) { int p = atomicAdd(&pcnt, 1); if (p < PL) { plist[2*p] = base + 3; plist[2*p+1] = v.w; } }
        }
    } else {
        for (int t = start + threadIdx.x; t < end; t += 256) {
            int j = row[t];
            if (j >= 0) { int p = atomicAdd(&pcnt, 1); if (p < PL) { plist[2*p] = t; plist[2*p+1] = j; } }
        }
    }
    __syncthreads();

    const int cnt = min(pcnt, PL);
    if (cnt == 0) return;
    for (int t = threadIdx.x; t < 4096; t += 256) sW[t] = W[(size_t)o * 4096 + t];
    __syncthreads();

    const int lane = threadIdx.x & 63;
    const int lwid = threadIdx.x >> 6;
    for (int p = lwid; p < cnt; p += 4) {
        int i = plist[2 * p];
        int j = plist[2 * p + 1];
        float cv  = ctx[j * 64 + lane];
        float acc = 0.0f;
        #pragma unroll
        for (int c = 0; c < 64; ++c)
            acc = fmaf(__shfl(cv, c), sW[c * 64 + lane], acc);
        atomicAdd(&sbuf[(size_t)i * 64 + lane], acc);
    }
}

// ------- K3: y = center-matvec + sbuf + b; ln = LN(gelu(y)); opt. pooling ---
__global__ __launch_bounds__(256) void k_post(
    const float* __restrict__ cin, float* __restrict__ sbuf,
    const float* __restrict__ W, const float* __restrict__ b,
    const float* __restrict__ g, const float* __restrict__ be,
    const int* __restrict__ bid, float* __restrict__ lnout,
    float* __restrict__ psum, float* __restrict__ pcnts,
    int N, int center, int zero_sbuf, int do_pool)
{
    __shared__ float sIn[4][256];
    __shared__ float red[4 * 4 * 64];
    __shared__ float redc[16];
    const int lane = threadIdx.x & 63;
    const int wv   = threadIdx.x >> 6;
    float* sin = sIn[wv];

    float wc[64];
    const float* Wc = W + (size_t)center * 4096;
    #pragma unroll
    for (int k = 0; k < 64; ++k) wc[k] = Wc[k * 64 + lane];
    const float bv = b[lane], gv = g[lane], bev = be[lane];

    const int wid  = blockIdx.x * 4 + wv;
    const int nw   = gridDim.x * 4;
    const int ngrp = (N + 3) >> 2;
    float a0 = 0, a1 = 0, a2 = 0, a3 = 0;
    float c0 = 0, c1 = 0, c2 = 0, c3 = 0;

    for (int grp = wid; grp < ngrp; grp += nw) {
        const int r0 = grp * 4;
        const int nr = min(4, N - r0);
        #pragma unroll
        for (int m = 0; m < 4; ++m) {
            int r = r0 + ((m < nr) ? m : 0);
            sin[m * 64 + lane] = cin[(size_t)r * 64 + lane];
        }
        float acc[4];
        #pragma unroll
        for (int m = 0; m < 4; ++m) {
            int r = r0 + ((m < nr) ? m : 0);
            acc[m] = bv + sbuf[(size_t)r * 64 + lane];
        }
        if (zero_sbuf) {
            #pragma unroll
            for (int m = 0; m < 4; ++m)
                if (m < nr) sbuf[(size_t)(r0 + m) * 64 + lane] = 0.0f;
        }
        matvec_bcast<4>(sin, wc, acc);
        #pragma unroll
        for (int m = 0; m < 4; ++m) {
            if (m >= nr) break;
            const int r = r0 + m;
            float v = gelu_exact(acc[m]);
            float s = v;
            #pragma unroll
            for (int mk = 1; mk < 64; mk <<= 1) s += __shfl_xor(s, mk);
            const float mean = s * 0.015625f;
            const float d = v - mean;
            float vs = d * d;
            #pragma unroll
            for (int mk = 1; mk < 64; mk <<= 1) vs += __shfl_xor(vs, mk);
            const float ln = d * rsqrtf(vs * 0.015625f + 1e-5f) * gv + bev;
            lnout[(size_t)r * 64 + lane] = ln;
            if (do_pool) {
                int bb = bid[r];
                if      (bb == 0) { a0 += ln; c0 += 1.0f; }
                else if (bb == 1) { a1 += ln; c1 += 1.0f; }
                else if (bb == 2) { a2 += ln; c2 += 1.0f; }
                else              { a3 += ln; c3 += 1.0f; }
            }
        }
    }

    if (do_pool) {
        red[(wv * 4 + 0) * 64 + lane] = a0;
        red[(wv * 4 + 1) * 64 + lane] = a1;
        red[(wv * 4 + 2) * 64 + lane] = a2;
        red[(wv * 4 + 3) * 64 + lane] = a3;
        if (lane == 0) {
            redc[wv * 4 + 0] = c0; redc[wv * 4 + 1] = c1;
            redc[wv * 4 + 2] = c2; redc[wv * 4 + 3] = c3;
        }
        __syncthreads();
        if (wv == 0) {
            #pragma unroll
            for (int bb = 0; bb < 4; ++bb) {
                float sum = red[(0 * 4 + bb) * 64 + lane] + red[(1 * 4 + bb) * 64 + lane]
                          + red[(2 * 4 + bb) * 64 + lane] + red[(3 * 4 + bb) * 64 + lane];
                atomicAdd(&psum[bb * 64 + lane], sum);
            }
        }
        if (threadIdx.x == 0) {
            #pragma unroll
            for (int bb = 0; bb < 4; ++bb) {
                float cc = redc[0 * 4 + bb] + redc[1 * 4 + bb] + redc[2 * 4 + bb] + redc[3 * 4 + bb];
                atomicAdd(&pcnts[bb], cc);
            }
        }
    }
}

// ---------------- K4: epilogue: v -> @hW -> *q -> @pW ----------------------
__global__ __launch_bounds__(256) void k_final(
    const float* __restrict__ ln0, const float* __restrict__ ln1,
    const float* __restrict__ ln2, const float* __restrict__ gates,
    const float* __restrict__ q, const int* __restrict__ bid,
    const float* __restrict__ psum, const float* __restrict__ pcnts,
    const float* __restrict__ hW, const float* __restrict__ hb,
    const float* __restrict__ pW, const float* __restrict__ pb,
    float* __restrict__ out, int N)
{
    __shared__ float sV[4][256];
    __shared__ float spool[256];
    const int lane = threadIdx.x & 63;
    const int wv   = threadIdx.x >> 6;
    float* sin = sV[wv];

    float wh[64], wp[64];
    #pragma unroll
    for (int k = 0; k < 64; ++k) {
        wh[k] = hW[k * 64 + lane];
        wp[k] = pW[k * 64 + lane];
    }
    {
        int b4 = threadIdx.x >> 6;
        spool[threadIdx.x] = gelu_exact(psum[threadIdx.x] / pcnts[b4]);
    }
    __syncthreads();
    const float bh = hb[lane], bp = pb[lane];

    const int wid  = blockIdx.x * 4 + wv;
    const int nw   = gridDim.x * 4;
    const int ngrp = (N + 3) >> 2;
    for (int grp = wid; grp < ngrp; grp += nw) {
        const int r0 = grp * 4;
        const int nr = min(4, N - r0);
        float qv[4];
        #pragma unroll
        for (int m = 0; m < 4; ++m) {
            const int r = r0 + ((m < nr) ? m : 0);
            const float4 gt = *(const float4*)(gates + (size_t)r * 4);
            const int bb = bid[r];
            float v = ln0[(size_t)r * 64 + lane] * gt.x
                    + ln1[(size_t)r * 64 + lane] * gt.y
                    + ln2[(size_t)r * 64 + lane] * gt.z
                    + spool[bb * 64 + lane] * gt.w;
            qv[m] = q[(size_t)r * 64 + lane];   // q aliases out; read own row first
            sin[m * 64 + lane] = v;
        }
        float t1[4] = {bh, bh, bh, bh};
        matvec_bcast<4>(sin, wh, t1);
        #pragma unroll
        for (int m = 0; m < 4; ++m)
            sin[m * 64 + lane] = qv[m] * t1[m];
        float o[4] = {bp, bp, bp, bp};
        matvec_bcast<4>(sin, wp, o);
        #pragma unroll
        for (int m = 0; m < 4; ++m)
            if (m < nr) out[(size_t)(r0 + m) * 64 + lane] = o[m];
    }
}

// ---------------------------------------------------------------------------
extern "C" void kernel_launch(void* const* d_in, const int* in_sizes, int n_in,
                              void* d_out, int out_size, void* d_ws, size_t ws_size,
                              hipStream_t stream)
{
    const float* feat = (const float*)d_in[0];
    const float* fW   = (const float*)d_in[1];
    const float* fb   = (const float*)d_in[2];
    const float* hW   = (const float*)d_in[3];
    const float* hb   = (const float*)d_in[4];
    const float* pW   = (const float*)d_in[5];
    const float* pb   = (const float*)d_in[6];
    const int*   bid  = (const int*)d_in[7];
    const float* w[3]  = {(const float*)d_in[8],  (const float*)d_in[13], (const float*)d_in[18]};
    const float* bc[3] = {(const float*)d_in[9],  (const float*)d_in[14], (const float*)d_in[19]};
    const float* g[3]  = {(const float*)d_in[10], (const float*)d_in[15], (const float*)d_in[20]};
    const float* be[3] = {(const float*)d_in[11], (const float*)d_in[16], (const float*)d_in[21]};
    const int*  idx[3] = {(const int*)d_in[12],   (const int*)d_in[17],   (const int*)d_in[22]};

    const int N = in_sizes[0] / 64;

    // Workspace layout (floats). q lives in d_out; ln2 reuses ctx0's buffer.
    float* ws     = (float*)d_ws;
    float* sbuf   = ws;                          // N*64, zeroed once
    float* psum   = sbuf + (size_t)N * 64;       // 256, zeroed
    float* pcnts  = psum + 256;                  // 4, zeroed
    float* gates  = pcnts + 4;                   // N*4
    float* ctx0   = gates + (size_t)N * 4;       // N*64 (becomes ln2)
    float* ln0    = ctx0 + (size_t)N * 64;       // N*64
    float* ln1    = ln0 + (size_t)N * 64;        // N*64
    float* ln2    = ctx0;                        // alias: ctx0 dead after level 0
    float* q      = (float*)d_out;               // alias: epilogue reads then writes

    hipMemsetAsync(sbuf, 0, ((size_t)N * 64 + 260) * sizeof(float), stream);

    const dim3 blk(256);
    const int GR = 512;

    k_fused_in<<<GR, blk, 0, stream>>>(feat, fW, fb, q, ctx0, gates, N);

    const int Ks[3] = {27, 125, 343};
    const int Cs[3] = {16, 8, 6};
    const float* cins[3] = {ctx0, ln0, ln1};
    float*       lns[3]  = {ln0, ln1, ln2};
    for (int l = 0; l < 3; ++l) {
        const int K = Ks[l], C = Cs[l];
        const int center = (K - 1) / 2;
        const int seg = (((N + C - 1) / C) + 3) & ~3;
        k_sparse<<<K * C, blk, 0, stream>>>(cins[l], idx[l], w[l], sbuf, N, center, C, seg);
        k_post  <<<GR,    blk, 0, stream>>>(cins[l], sbuf, w[l], bc[l], g[l], be[l], bid,
                                            lns[l], psum, pcnts, N, center,
                                            (l < 2) ? 1 : 0, (l == 2) ? 1 : 0);
    }

    k_final<<<GR, blk, 0, stream>>>(ln0, ln1, ln2, gates, q, bid, psum, pcnts,
                                    hW, hb, pW, pb, (float*)d_out, N);
}

// Round 6
// 345.435 us; speedup vs baseline: 1.3393x; 1.1259x over previous
//
#include <hip/hip_runtime.h>
#include <math.h>

// SparseFocalModulation — round 6 (= round 5 resubmit, GPU was unavailable):
// dense matvecs via v_readlane broadcast (zero LDS in hot matvec loops).

#define PL 1024   // plist capacity (pairs) per sparse block; expected ~18

__device__ __forceinline__ float gelu_exact(float x) {
    return 0.5f * x * (1.0f + erff(x * 0.70710678118654752440f));
}

__device__ __forceinline__ float rl(float v, int k) {
    return __uint_as_float(__builtin_amdgcn_readlane(__float_as_uint(v), (unsigned)k));
}

// acc[m] += sum_k rv[m](lane k) * w[k]
template<int M>
__device__ __forceinline__ void matvec_rl(const float (&rv)[M], const float (&w)[64], float (&acc)[M]) {
    #pragma unroll
    for (int k = 0; k < 64; ++k) {
        #pragma unroll
        for (int m = 0; m < M; ++m)
            acc[m] = fmaf(rl(rv[m], k), w[k], acc[m]);
    }
}

// dual-output variant: shares each broadcast between two weight sets
template<int M>
__device__ __forceinline__ void matvec_rl2(const float (&rv)[M],
                                           const float (&w1)[64], const float (&w2)[64],
                                           float (&a1)[M], float (&a2)[M]) {
    #pragma unroll
    for (int k = 0; k < 64; ++k) {
        #pragma unroll
        for (int m = 0; m < M; ++m) {
            const float s = rl(rv[m], k);
            a1[m] = fmaf(s, w1[k], a1[m]);
            a2[m] = fmaf(s, w2[k], a2[m]);
        }
    }
}

// ---------------- K1: xf = feat @ f_W + f_b ; split into q / ctx / gates ----
__global__ __launch_bounds__(256) void k_fused_in(
    const float* __restrict__ feat, const float* __restrict__ fW,
    const float* __restrict__ fb, float* __restrict__ q,
    float* __restrict__ ctx, float* __restrict__ gates, int N)
{
    __shared__ float sIn[4][256];        // only for the tiny gate gather
    const int lane = threadIdx.x & 63;
    const int wv   = threadIdx.x >> 6;
    float* sin = sIn[wv];

    float wq[64], wc[64];
    #pragma unroll
    for (int k = 0; k < 64; ++k) {
        wq[k] = fW[k * 132 + lane];
        wc[k] = fW[k * 132 + 64 + lane];
    }
    const int g    = lane & 3;
    const int kblk = lane >> 2;
    float wg[4];
    #pragma unroll
    for (int kk = 0; kk < 4; ++kk)
        wg[kk] = fW[(kblk * 4 + kk) * 132 + 128 + g];
    const float bq = fb[lane], bc = fb[64 + lane], bg = fb[128 + g];

    const int wid  = blockIdx.x * 4 + wv;
    const int nw   = gridDim.x * 4;
    const int ngrp = (N + 3) >> 2;
    for (int grp = wid; grp < ngrp; grp += nw) {
        const int r0 = grp * 4;
        const int nr = min(4, N - r0);
        float fv[4];
        #pragma unroll
        for (int m = 0; m < 4; ++m) {
            int r = r0 + ((m < nr) ? m : 0);
            fv[m] = feat[(size_t)r * 64 + lane];
        }
        float aq[4] = {bq, bq, bq, bq};
        float ac[4] = {bc, bc, bc, bc};
        matvec_rl2<4>(fv, wq, wc, aq, ac);

        #pragma unroll
        for (int m = 0; m < 4; ++m) sin[m * 64 + lane] = fv[m];
        float ag[4];
        #pragma unroll
        for (int m = 0; m < 4; ++m) {
            const float4 gi = *(const float4*)(sin + m * 64 + kblk * 4);
            float s = gi.x * wg[0] + gi.y * wg[1] + gi.z * wg[2] + gi.w * wg[3];
            s += __shfl_xor(s, 4);
            s += __shfl_xor(s, 8);
            s += __shfl_xor(s, 16);
            s += __shfl_xor(s, 32);
            ag[m] = s + bg;
        }
        #pragma unroll
        for (int m = 0; m < 4; ++m) {
            if (m < nr) {
                q[(size_t)(r0 + m) * 64 + lane]   = aq[m];
                ctx[(size_t)(r0 + m) * 64 + lane] = ac[m];
                if (lane < 4) gates[(size_t)(r0 + m) * 4 + lane] = ag[m];
            }
        }
    }
}

// ---------------- K2: sparse non-center offsets -> atomicAdd into sbuf ------
__global__ __launch_bounds__(256) void k_sparse(
    const float* __restrict__ ctx, const int* __restrict__ idx,
    const float* __restrict__ W, float* __restrict__ sbuf,
    int N, int center, int nchunk, int seg)
{
    const int o = blockIdx.x / nchunk;
    if (o == center) return;
    const int chunk = blockIdx.x % nchunk;

    __shared__ int plist[2 * PL];
    __shared__ int pcnt;
    if (threadIdx.x == 0) pcnt = 0;
    __syncthreads();

    const int start = chunk * seg;
    const int end   = min(N, start + seg);
    const int* row  = idx + (size_t)o * N;
    if (((N | start) & 3) == 0) {
        const int4* row4 = reinterpret_cast<const int4*>(row + start);
        const int n4 = (end - start) >> 2;
        for (int t = threadIdx.x; t < n4; t += 256) {
            int4 v = row4[t];
            int base = start + t * 4;
            if (v.x >= 0) { int p = atomicAdd(&pcnt, 1); if (p < PL) { plist[2*p] = base;     plist[2*p+1] = v.x; } }
            if (v.y >= 0) { int p = atomicAdd(&pcnt, 1); if (p < PL) { plist[2*p] = base + 1; plist[2*p+1] = v.y; } }
            if (v.z >= 0) { int p = atomicAdd(&pcnt, 1); if (p < PL) { plist[2*p] = base + 2; plist[2*p+1] = v.z; } }
            if (v.w >= 0) { int p = atomicAdd(&pcnt, 1); if (p < PL) { plist[2*p] = base + 3; plist[2*p+1] = v.w; } }
        }
    } else {
        for (int t = start + threadIdx.x; t < end; t += 256) {
            int j = row[t];
            if (j >= 0) { int p = atomicAdd(&pcnt, 1); if (p < PL) { plist[2*p] = t; plist[2*p+1] = j; } }
        }
    }
    __syncthreads();

    const int cnt = min(pcnt, PL);
    if (cnt == 0) return;

    const int lane = threadIdx.x & 63;
    float wv_[64];
    #pragma unroll
    for (int k = 0; k < 64; ++k)
        wv_[k] = W[(size_t)o * 4096 + k * 64 + lane];

    const int lwid = threadIdx.x >> 6;
    for (int p = lwid; p < cnt; p += 4) {
        int i = plist[2 * p];
        int j = plist[2 * p + 1];
        float cv[1] = { ctx[(size_t)j * 64 + lane] };
        float acc[1] = { 0.0f };
        matvec_rl<1>(cv, wv_, acc);
        atomicAdd(&sbuf[(size_t)i * 64 + lane], acc[0]);
    }
}

// ------- K3: y = center-matvec + sbuf + b; ln = LN(gelu(y)); opt. pooling ---
__global__ __launch_bounds__(256) void k_post(
    const float* __restrict__ cin, float* __restrict__ sbuf,
    const float* __restrict__ W, const float* __restrict__ b,
    const float* __restrict__ g, const float* __restrict__ be,
    const int* __restrict__ bid, float* __restrict__ lnout,
    float* __restrict__ psum, float* __restrict__ pcnts,
    int N, int center, int zero_sbuf, int do_pool)
{
    __shared__ float red[4 * 4 * 64];
    __shared__ float redc[16];
    const int lane = threadIdx.x & 63;
    const int wv   = threadIdx.x >> 6;

    float wc[64];
    const float* Wc = W + (size_t)center * 4096;
    #pragma unroll
    for (int k = 0; k < 64; ++k) wc[k] = Wc[k * 64 + lane];
    const float bv = b[lane], gv = g[lane], bev = be[lane];

    const int wid  = blockIdx.x * 4 + wv;
    const int nw   = gridDim.x * 4;
    const int ngrp = (N + 3) >> 2;
    float a0 = 0, a1 = 0, a2 = 0, a3 = 0;
    float c0 = 0, c1 = 0, c2 = 0, c3 = 0;

    for (int grp = wid; grp < ngrp; grp += nw) {
        const int r0 = grp * 4;
        const int nr = min(4, N - r0);
        float fv[4], acc[4];
        #pragma unroll
        for (int m = 0; m < 4; ++m) {
            int r = r0 + ((m < nr) ? m : 0);
            fv[m]  = cin[(size_t)r * 64 + lane];
            acc[m] = bv + sbuf[(size_t)r * 64 + lane];
        }
        if (zero_sbuf) {
            #pragma unroll
            for (int m = 0; m < 4; ++m)
                if (m < nr) sbuf[(size_t)(r0 + m) * 64 + lane] = 0.0f;
        }
        matvec_rl<4>(fv, wc, acc);
        #pragma unroll
        for (int m = 0; m < 4; ++m) {
            if (m >= nr) break;
            const int r = r0 + m;
            float v = gelu_exact(acc[m]);
            float s = v;
            #pragma unroll
            for (int mk = 1; mk < 64; mk <<= 1) s += __shfl_xor(s, mk);
            const float mean = s * 0.015625f;
            const float d = v - mean;
            float vs = d * d;
            #pragma unroll
            for (int mk = 1; mk < 64; mk <<= 1) vs += __shfl_xor(vs, mk);
            const float ln = d * rsqrtf(vs * 0.015625f + 1e-5f) * gv + bev;
            lnout[(size_t)r * 64 + lane] = ln;
            if (do_pool) {
                int bb = bid[r];
                if      (bb == 0) { a0 += ln; c0 += 1.0f; }
                else if (bb == 1) { a1 += ln; c1 += 1.0f; }
                else if (bb == 2) { a2 += ln; c2 += 1.0f; }
                else              { a3 += ln; c3 += 1.0f; }
            }
        }
    }

    if (do_pool) {
        red[(wv * 4 + 0) * 64 + lane] = a0;
        red[(wv * 4 + 1) * 64 + lane] = a1;
        red[(wv * 4 + 2) * 64 + lane] = a2;
        red[(wv * 4 + 3) * 64 + lane] = a3;
        if (lane == 0) {
            redc[wv * 4 + 0] = c0; redc[wv * 4 + 1] = c1;
            redc[wv * 4 + 2] = c2; redc[wv * 4 + 3] = c3;
        }
        __syncthreads();
        if (wv == 0) {
            #pragma unroll
            for (int bb = 0; bb < 4; ++bb) {
                float sum = red[(0 * 4 + bb) * 64 + lane] + red[(1 * 4 + bb) * 64 + lane]
                          + red[(2 * 4 + bb) * 64 + lane] + red[(3 * 4 + bb) * 64 + lane];
                atomicAdd(&psum[bb * 64 + lane], sum);
            }
        }
        if (threadIdx.x == 0) {
            #pragma unroll
            for (int bb = 0; bb < 4; ++bb) {
                float cc = redc[0 * 4 + bb] + redc[1 * 4 + bb] + redc[2 * 4 + bb] + redc[3 * 4 + bb];
                atomicAdd(&pcnts[bb], cc);
            }
        }
    }
}

// ---------------- K4: epilogue: v -> @hW -> *q -> @pW ----------------------
__global__ __launch_bounds__(256) void k_final(
    const float* __restrict__ ln0, const float* __restrict__ ln1,
    const float* __restrict__ ln2, const float* __restrict__ gates,
    const float* __restrict__ q, const int* __restrict__ bid,
    const float* __restrict__ psum, const float* __restrict__ pcnts,
    const float* __restrict__ hW, const float* __restrict__ hb,
    const float* __restrict__ pW, const float* __restrict__ pb,
    float* __restrict__ out, int N)
{
    __shared__ float spool[256];
    const int lane = threadIdx.x & 63;
    const int wv   = threadIdx.x >> 6;

    float wh[64], wp[64];
    #pragma unroll
    for (int k = 0; k < 64; ++k) {
        wh[k] = hW[k * 64 + lane];
        wp[k] = pW[k * 64 + lane];
    }
    spool[threadIdx.x] = gelu_exact(psum[threadIdx.x] / pcnts[threadIdx.x >> 6]);
    __syncthreads();
    const float bh = hb[lane], bp = pb[lane];

    const int wid  = blockIdx.x * 4 + wv;
    const int nw   = gridDim.x * 4;
    const int ngrp = (N + 3) >> 2;
    for (int grp = wid; grp < ngrp; grp += nw) {
        const int r0 = grp * 4;
        const int nr = min(4, N - r0);
        float v[4], qv[4];
        #pragma unroll
        for (int m = 0; m < 4; ++m) {
            const int r = r0 + ((m < nr) ? m : 0);
            const float4 gt = *(const float4*)(gates + (size_t)r * 4);
            const int bb = bid[r];
            v[m] = ln0[(size_t)r * 64 + lane] * gt.x
                 + ln1[(size_t)r * 64 + lane] * gt.y
                 + ln2[(size_t)r * 64 + lane] * gt.z
                 + spool[bb * 64 + lane] * gt.w;
            qv[m] = q[(size_t)r * 64 + lane];   // q aliases out; read own row first
        }
        float t1[4] = {bh, bh, bh, bh};
        matvec_rl<4>(v, wh, t1);
        float u[4];
        #pragma unroll
        for (int m = 0; m < 4; ++m) u[m] = qv[m] * t1[m];
        float o[4] = {bp, bp, bp, bp};
        matvec_rl<4>(u, wp, o);
        #pragma unroll
        for (int m = 0; m < 4; ++m)
            if (m < nr) out[(size_t)(r0 + m) * 64 + lane] = o[m];
    }
}

// ---------------------------------------------------------------------------
extern "C" void kernel_launch(void* const* d_in, const int* in_sizes, int n_in,
                              void* d_out, int out_size, void* d_ws, size_t ws_size,
                              hipStream_t stream)
{
    const float* feat = (const float*)d_in[0];
    const float* fW   = (const float*)d_in[1];
    const float* fb   = (const float*)d_in[2];
    const float* hW   = (const float*)d_in[3];
    const float* hb   = (const float*)d_in[4];
    const float* pW   = (const float*)d_in[5];
    const float* pb   = (const float*)d_in[6];
    const int*   bid  = (const int*)d_in[7];
    const float* w[3]  = {(const float*)d_in[8],  (const float*)d_in[13], (const float*)d_in[18]};
    const float* bc[3] = {(const float*)d_in[9],  (const float*)d_in[14], (const float*)d_in[19]};
    const float* g[3]  = {(const float*)d_in[10], (const float*)d_in[15], (const float*)d_in[20]};
    const float* be[3] = {(const float*)d_in[11], (const float*)d_in[16], (const float*)d_in[21]};
    const int*  idx[3] = {(const int*)d_in[12],   (const int*)d_in[17],   (const int*)d_in[22]};

    const int N = in_sizes[0] / 64;

    // Workspace layout (floats). q lives in d_out; ln2 reuses ctx0's buffer.
    float* ws     = (float*)d_ws;
    float* sbuf   = ws;                          // N*64, zeroed once
    float* psum   = sbuf + (size_t)N * 64;       // 256, zeroed
    float* pcnts  = psum + 256;                  // 4, zeroed
    float* gates  = pcnts + 4;                   // N*4 (16B-aligned: N*64+260 floats)
    float* ctx0   = gates + (size_t)N * 4;       // N*64 (becomes ln2)
    float* ln0    = ctx0 + (size_t)N * 64;       // N*64
    float* ln1    = ln0 + (size_t)N * 64;        // N*64
    float* ln2    = ctx0;                        // alias: ctx0 dead after level 0
    float* q      = (float*)d_out;               // alias: epilogue reads then writes

    hipMemsetAsync(sbuf, 0, ((size_t)N * 64 + 260) * sizeof(float), stream);

    const dim3 blk(256);
    const int GR = 940;   // ~3760 waves over 7500 row-groups

    k_fused_in<<<GR, blk, 0, stream>>>(feat, fW, fb, q, ctx0, gates, N);

    const int Ks[3] = {27, 125, 343};
    const int Cs[3] = {16, 8, 6};
    const float* cins[3] = {ctx0, ln0, ln1};
    float*       lns[3]  = {ln0, ln1, ln2};
    for (int l = 0; l < 3; ++l) {
        const int K = Ks[l], C = Cs[l];
        const int center = (K - 1) / 2;
        const int seg = (((N + C - 1) / C) + 3) & ~3;
        k_sparse<<<K * C, blk, 0, stream>>>(cins[l], idx[l], w[l], sbuf, N, center, C, seg);
        k_post  <<<GR,    blk, 0, stream>>>(cins[l], sbuf, w[l], bc[l], g[l], be[l], bid,
                                            lns[l], psum, pcnts, N, center,
                                            (l < 2) ? 1 : 0, (l == 2) ? 1 : 0);
    }

    k_final<<<GR, blk, 0, stream>>>(ln0, ln1, ln2, gates, q, bid, psum, pcnts,
                                    hW, hb, pW, pb, (float*)d_out, N);
}